// Round 5
// baseline (209.976 us; speedup 1.0000x reference)
//
#include <hip/hip_runtime.h>
#include <math.h>

#define S_LEN 512
#define BATCH 256
#define NTAG  128
#define EMSTRIDE (BATCH * NTAG)  /* floats per time step */

typedef float f32x4 __attribute__((ext_vector_type(4)));
typedef float f32x2 __attribute__((ext_vector_type(2)));

// padded LDS float index: +4 floats between the two 64-halves
__device__ __forceinline__ int lidx(int k) { return k + ((k >> 6) << 2); }
__device__ __forceinline__ f32x2 lo2(f32x4 v){ f32x2 r; r[0]=v[0]; r[1]=v[1]; return r; }
__device__ __forceinline__ f32x2 hi2(f32x4 v){ f32x2 r; r[0]=v[2]; r[1]=v[3]; return r; }
__device__ __forceinline__ f32x2 pmax2(f32x2 a, f32x2 b){
  f32x2 r; r[0]=fmaxf(a[0],b[0]); r[1]=fmaxf(a[1],b[1]); return r;
}

// DPP quad-perm: swap adjacent lanes (0<->1, 2<->3) — VALU-speed pair combine
#define DPP_XOR1(x) __int_as_float(__builtin_amdgcn_mov_dpp(__float_as_int(x), 0xB1, 0xF, 0xF, false))

// Raw barrier: drain LDS only (NOT vmcnt) so global prefetch stays in flight.
#define BAR() do {                                       \
    asm volatile("s_waitcnt lgkmcnt(0)" ::: "memory");   \
    __builtin_amdgcn_s_barrier();                        \
    __builtin_amdgcn_sched_barrier(0);                   \
  } while (0)

// ---------------------------------------------------------------------------
// Fat kernel, 256 threads/block, grid = 5*BATCH:
//   role = blk>>8: 0=fwd-left, 1=fwd-backward-right, 2=vit-left,
//                  3=vit-backward-right, 4=gold.  b = blk&255.
// Meet point sm = (len-1)>>1:
//   F_sm[j] (exp space, pow2 renorm) covers em[0..sm];
//   B_sm[k] covers transitions sm..len-1 + em[sm+1..len-1] + stop.
//   total = (EwF+EwB)ln2 + log(sum_k WF[k]*WB[k]); viterbi same with max.
// Thread map (roles 0-3): p = tid>>1 (output row), h = tid&1 (k-half).
// ---------------------------------------------------------------------------
__global__ __launch_bounds__(256, 1)
void crf_fat_kernel(const float* __restrict__ emis,
                    const float* __restrict__ mask,
                    const int* __restrict__ tags,
                    const float* __restrict__ trans,
                    const float* __restrict__ startt,
                    const float* __restrict__ stopt,
                    float* __restrict__ ws,
                    int* __restrict__ ewbuf,
                    float* __restrict__ out)
{
  const int blk  = blockIdx.x;
  const int tid  = threadIdx.x;
  const int role = blk >> 8;
  const int b    = blk & 255;
  const int lane = tid & 63;
  const int wid  = tid >> 6;

  __shared__ __align__(16) float sbuf[2][144];
  __shared__ float red[8];

  // ---------------- gold role ----------------
  if (role == 4) {
    float part = 0.f, lenp = 0.f;
#pragma unroll
    for (int rep = 0; rep < 2; ++rep) {
      int s = tid + rep * 256;
      float m  = mask[(size_t)s * BATCH + b];
      int  cur = tags[(size_t)s * BATCH + b];
      if (s == 0) {
        part += startt[cur] + emis[(size_t)b * NTAG + cur] * m;
      } else {
        int prev = tags[(size_t)(s - 1) * BATCH + b];
        part += m * (trans[(size_t)prev * NTAG + cur] +
                     emis[((size_t)s * BATCH + b) * NTAG + cur]);
      }
      lenp += m;
    }
#pragma unroll
    for (int d = 1; d <= 32; d <<= 1) {
      part += __shfl_xor(part, d);
      lenp += __shfl_xor(lenp, d);
    }
    if (lane == 0) { red[wid] = part; red[4 + wid] = lenp; }
    __syncthreads();
    if (tid == 0) {
      float rps = (red[0] + red[1]) + (red[2] + red[3]);
      float lf  = (red[4] + red[5]) + (red[6] + red[7]);
      int len = (int)(lf + 0.5f);
      int pf  = tags[(size_t)(len - 1) * BATCH + b];
      out[1 + b] = rps + stopt[pf];
    }
    return;
  }

  const int p    = tid >> 1;      // output row 0..127
  const int h    = tid & 1;       // k-half
  const int widx = lidx(p);

  // ---- len = sum_s mask[s,b] (mask monotone) ----
  int len;
  {
    float mv = mask[(size_t)tid * BATCH + b] +
               mask[(size_t)(tid + 256) * BATCH + b];
#pragma unroll
    for (int d = 1; d <= 32; d <<= 1) mv += __shfl_xor(mv, d);
    if (lane == 0) red[wid] = mv;
    __syncthreads();
    float ls = (red[0] + red[1]) + (red[2] + red[3]);
    len = (int)(ls + 0.5f);
    len = __builtin_amdgcn_readfirstlane(len);
  }
  const int sm     = (len - 1) >> 1;
  const int nsteps = len - 1 - sm;      // backward step count
  const float* eb  = emis + (size_t)b * NTAG + p;

  if (role == 0) {
    // ========== forward-left (exp space, rows of E) ==========
    f32x2 E2[32];
    {
      const float* tr = trans + (size_t)p * NTAG + 64 * h;
#pragma unroll
      for (int c = 0; c < 16; ++c) {
        f32x4 t = *(const f32x4*)(tr + 4 * c);
        f32x2 a, bb;
        a[0] = __expf(t[0]); a[1] = __expf(t[1]);
        bb[0] = __expf(t[2]); bb[1] = __expf(t[3]);
        E2[2*c] = a; E2[2*c+1] = bb;
      }
    }
    if (h == 0) sbuf[0][widx] = __expf(startt[p] + eb[0]);
    float e0 = eb[(size_t)1 * EMSTRIDE];
    float e1 = eb[(size_t)2 * EMSTRIDE];
    float e2 = eb[(size_t)3 * EMSTRIDE];
    float e3 = eb[(size_t)4 * EMSTRIDE];
    int Ew = 0, fin = 0;
    __syncthreads();

#define FSTEP(U, EXV, RENORM)                                                 \
  {                                                                           \
    if (g + (U) > sm) { fin = (U) & 1; goto epi_f; }                          \
    const f32x4* wr = (const f32x4*)(sbuf[(U) & 1] + 68 * h);                 \
    f32x2 a0 = {0.f, 0.f}, a1 = {0.f, 0.f}, r2 = {0.f, 0.f};                  \
    _Pragma("unroll")                                                         \
    for (int c = 0; c < 16; ++c) {                                            \
      f32x4 w = wr[c];                                                        \
      f32x2 wl = lo2(w), wh = hi2(w);                                         \
      a0 = a0 + E2[2*c] * wl;                                                 \
      a1 = a1 + E2[2*c+1] * wh;                                               \
      if (RENORM) r2 = pmax2(r2, pmax2(wl, wh));                              \
    }                                                                         \
    f32x2 as = a0 + a1;                                                       \
    float sum = as[0] + as[1];                                                \
    sum += DPP_XOR1(sum);                                                     \
    float uf;                                                                 \
    if (RENORM) {                                                             \
      float rw = fmaxf(r2[0], r2[1]);                                         \
      rw = fmaxf(rw, DPP_XOR1(rw));                                           \
      int ew = (int)((__float_as_uint(rw) >> 23) & 0xFF) - 126;               \
      Ew += ew;                                                               \
      float swc = __uint_as_float((unsigned)(127 - ew) << 23);                \
      uf = (EXV) * sum * swc;                                                 \
    } else {                                                                  \
      uf = (EXV) * sum;                                                       \
    }                                                                         \
    if (h == 0) sbuf[((U) + 1) & 1][widx] = uf;                               \
    BAR();                                                                    \
  }

    for (int g = 1; g < S_LEN; g += 4) {
      int c0 = g + 4 < S_LEN ? g + 4 : S_LEN - 1;
      int c1 = g + 5 < S_LEN ? g + 5 : S_LEN - 1;
      int c2 = g + 6 < S_LEN ? g + 6 : S_LEN - 1;
      int c3 = g + 7 < S_LEN ? g + 7 : S_LEN - 1;
      float n0 = eb[(size_t)c0 * EMSTRIDE];
      float n1 = eb[(size_t)c1 * EMSTRIDE];
      float n2 = eb[(size_t)c2 * EMSTRIDE];
      float n3 = eb[(size_t)c3 * EMSTRIDE];
      float x0 = __expf(e0), x1 = __expf(e1);
      float x2 = __expf(e2), x3 = __expf(e3);
      FSTEP(0, x0, 0)
      FSTEP(1, x1, 0)
      FSTEP(2, x2, 0)
      FSTEP(3, x3, 1)
      e0 = n0; e1 = n1; e2 = n2; e3 = n3;
    }
    fin = 0;
epi_f:
    {
      if (tid < 128) ws[(size_t)b * 512 + tid] = sbuf[fin][lidx(tid)];
      if (tid == 0) ewbuf[b] = Ew;
    }
  } else if (role == 1) {
    // ========== backward-right (exp space, columns of E) ==========
    f32x2 E2[32];
    {
      const float* tc = trans + p + (size_t)(64 * h) * NTAG;
#pragma unroll
      for (int e = 0; e < 32; ++e) {
        f32x2 a;
        a[0] = __expf(tc[(size_t)(2*e)     * NTAG]);
        a[1] = __expf(tc[(size_t)(2*e + 1) * NTAG]);
        E2[e] = a;
      }
    }
    if (h == 0) {
      float st = stopt[p];
      float y = (nsteps > 0) ? __expf(st + eb[(size_t)(len - 1) * EMSTRIDE])
                             : __expf(st);
      sbuf[0][widx] = y;
    }
    // emission stream: iter i uses em[len-2-i] (clamped)
    int s0i = len - 2;     s0i = s0i < 0 ? 0 : s0i;
    int s1i = len - 3;     s1i = s1i < 0 ? 0 : s1i;
    int s2i = len - 4;     s2i = s2i < 0 ? 0 : s2i;
    int s3i = len - 5;     s3i = s3i < 0 ? 0 : s3i;
    float e0 = eb[(size_t)s0i * EMSTRIDE];
    float e1 = eb[(size_t)s1i * EMSTRIDE];
    float e2 = eb[(size_t)s2i * EMSTRIDE];
    float e3 = eb[(size_t)s3i * EMSTRIDE];
    int Ew = 0, fin = 0;
    __syncthreads();

#define BSTEP(U, EXV, RENORM)                                                 \
  {                                                                           \
    if (gi + (U) >= nsteps) { fin = (U) & 1; goto epi_b; }                    \
    const f32x4* wr = (const f32x4*)(sbuf[(U) & 1] + 68 * h);                 \
    f32x2 a0 = {0.f, 0.f}, a1 = {0.f, 0.f}, r2 = {0.f, 0.f};                  \
    _Pragma("unroll")                                                         \
    for (int c = 0; c < 16; ++c) {                                            \
      f32x4 w = wr[c];                                                        \
      f32x2 wl = lo2(w), wh = hi2(w);                                         \
      a0 = a0 + E2[2*c] * wl;                                                 \
      a1 = a1 + E2[2*c+1] * wh;                                               \
      if (RENORM) r2 = pmax2(r2, pmax2(wl, wh));                              \
    }                                                                         \
    f32x2 as = a0 + a1;                                                       \
    float sum = as[0] + as[1];                                                \
    sum += DPP_XOR1(sum);                                                     \
    float exm = (gi + (U) == nsteps - 1) ? 1.0f : (EXV);                      \
    float uf;                                                                 \
    if (RENORM) {                                                             \
      float rw = fmaxf(r2[0], r2[1]);                                         \
      rw = fmaxf(rw, DPP_XOR1(rw));                                           \
      int ew = (int)((__float_as_uint(rw) >> 23) & 0xFF) - 126;               \
      Ew += ew;                                                               \
      float swc = __uint_as_float((unsigned)(127 - ew) << 23);                \
      uf = exm * sum * swc;                                                   \
    } else {                                                                  \
      uf = exm * sum;                                                         \
    }                                                                         \
    if (h == 0) sbuf[((U) + 1) & 1][widx] = uf;                               \
    BAR();                                                                    \
  }

    for (int gi = 0; gi < S_LEN; gi += 4) {
      int c0 = len - 2 - (gi + 4); c0 = c0 < 0 ? 0 : c0;
      int c1 = len - 2 - (gi + 5); c1 = c1 < 0 ? 0 : c1;
      int c2 = len - 2 - (gi + 6); c2 = c2 < 0 ? 0 : c2;
      int c3 = len - 2 - (gi + 7); c3 = c3 < 0 ? 0 : c3;
      float n0 = eb[(size_t)c0 * EMSTRIDE];
      float n1 = eb[(size_t)c1 * EMSTRIDE];
      float n2 = eb[(size_t)c2 * EMSTRIDE];
      float n3 = eb[(size_t)c3 * EMSTRIDE];
      float x0 = __expf(e0), x1 = __expf(e1);
      float x2 = __expf(e2), x3 = __expf(e3);
      BSTEP(0, x0, 0)
      BSTEP(1, x1, 0)
      BSTEP(2, x2, 0)
      BSTEP(3, x3, 1)
      e0 = n0; e1 = n1; e2 = n2; e3 = n3;
    }
    fin = 0;
epi_b:
    {
      if (tid < 128) ws[(size_t)b * 512 + 128 + tid] = sbuf[fin][lidx(tid)];
      if (tid == 0) ewbuf[BATCH + b] = Ew;
    }
  } else if (role == 2) {
    // ========== viterbi-left (log space, rows of T) ==========
    f32x2 T2[32];
    {
      const float* tr = trans + (size_t)p * NTAG + 64 * h;
#pragma unroll
      for (int c = 0; c < 16; ++c) {
        f32x4 t = *(const f32x4*)(tr + 4 * c);
        T2[2*c]   = lo2(t);
        T2[2*c+1] = hi2(t);
      }
    }
    if (h == 0) sbuf[0][widx] = startt[p] + eb[0];
    float e0 = eb[(size_t)1 * EMSTRIDE];
    float e1 = eb[(size_t)2 * EMSTRIDE];
    float e2 = eb[(size_t)3 * EMSTRIDE];
    float e3 = eb[(size_t)4 * EMSTRIDE];
    int fin = 0;
    __syncthreads();

#define VSTEP(U, EMV)                                                         \
  {                                                                           \
    if (g + (U) > sm) { fin = (U) & 1; goto epi_v; }                          \
    const f32x4* vr = (const f32x4*)(sbuf[(U) & 1] + 68 * h);                 \
    f32x2 m2 = {-3.0e38f, -3.0e38f};                                          \
    _Pragma("unroll")                                                         \
    for (int c = 0; c < 16; ++c) {                                            \
      f32x4 v = vr[c];                                                        \
      m2 = pmax2(m2, pmax2(lo2(v) + T2[2*c], hi2(v) + T2[2*c+1]));            \
    }                                                                         \
    float vm = fmaxf(m2[0], m2[1]);                                           \
    vm = fmaxf(vm, DPP_XOR1(vm));                                             \
    float uv = (EMV) + vm;                                                    \
    if (h == 0) sbuf[((U) + 1) & 1][widx] = uv;                               \
    BAR();                                                                    \
  }

    for (int g = 1; g < S_LEN; g += 4) {
      int c0 = g + 4 < S_LEN ? g + 4 : S_LEN - 1;
      int c1 = g + 5 < S_LEN ? g + 5 : S_LEN - 1;
      int c2 = g + 6 < S_LEN ? g + 6 : S_LEN - 1;
      int c3 = g + 7 < S_LEN ? g + 7 : S_LEN - 1;
      float n0 = eb[(size_t)c0 * EMSTRIDE];
      float n1 = eb[(size_t)c1 * EMSTRIDE];
      float n2 = eb[(size_t)c2 * EMSTRIDE];
      float n3 = eb[(size_t)c3 * EMSTRIDE];
      VSTEP(0, e0)
      VSTEP(1, e1)
      VSTEP(2, e2)
      VSTEP(3, e3)
      e0 = n0; e1 = n1; e2 = n2; e3 = n3;
    }
    fin = 0;
epi_v:
    {
      if (tid < 128) ws[(size_t)b * 512 + 256 + tid] = sbuf[fin][lidx(tid)];
    }
  } else {
    // ========== viterbi-backward-right (log space, columns of T) ==========
    f32x2 T2[32];
    {
      const float* tc = trans + p + (size_t)(64 * h) * NTAG;
#pragma unroll
      for (int e = 0; e < 32; ++e) {
        f32x2 a;
        a[0] = tc[(size_t)(2*e)     * NTAG];
        a[1] = tc[(size_t)(2*e + 1) * NTAG];
        T2[e] = a;
      }
    }
    if (h == 0) {
      float st = stopt[p];
      float y = (nsteps > 0) ? st + eb[(size_t)(len - 1) * EMSTRIDE] : st;
      sbuf[0][widx] = y;
    }
    int s0i = len - 2;     s0i = s0i < 0 ? 0 : s0i;
    int s1i = len - 3;     s1i = s1i < 0 ? 0 : s1i;
    int s2i = len - 4;     s2i = s2i < 0 ? 0 : s2i;
    int s3i = len - 5;     s3i = s3i < 0 ? 0 : s3i;
    float e0 = eb[(size_t)s0i * EMSTRIDE];
    float e1 = eb[(size_t)s1i * EMSTRIDE];
    float e2 = eb[(size_t)s2i * EMSTRIDE];
    float e3 = eb[(size_t)s3i * EMSTRIDE];
    int fin = 0;
    __syncthreads();

#define WSTEP(U, EMV)                                                         \
  {                                                                           \
    if (gi + (U) >= nsteps) { fin = (U) & 1; goto epi_w; }                    \
    const f32x4* vr = (const f32x4*)(sbuf[(U) & 1] + 68 * h);                 \
    f32x2 m2 = {-3.0e38f, -3.0e38f};                                          \
    _Pragma("unroll")                                                         \
    for (int c = 0; c < 16; ++c) {                                            \
      f32x4 v = vr[c];                                                        \
      m2 = pmax2(m2, pmax2(lo2(v) + T2[2*c], hi2(v) + T2[2*c+1]));            \
    }                                                                         \
    float vm = fmaxf(m2[0], m2[1]);                                           \
    vm = fmaxf(vm, DPP_XOR1(vm));                                             \
    float uv = (gi + (U) == nsteps - 1) ? vm : vm + (EMV);                    \
    if (h == 0) sbuf[((U) + 1) & 1][widx] = uv;                               \
    BAR();                                                                    \
  }

    for (int gi = 0; gi < S_LEN; gi += 4) {
      int c0 = len - 2 - (gi + 4); c0 = c0 < 0 ? 0 : c0;
      int c1 = len - 2 - (gi + 5); c1 = c1 < 0 ? 0 : c1;
      int c2 = len - 2 - (gi + 6); c2 = c2 < 0 ? 0 : c2;
      int c3 = len - 2 - (gi + 7); c3 = c3 < 0 ? 0 : c3;
      float n0 = eb[(size_t)c0 * EMSTRIDE];
      float n1 = eb[(size_t)c1 * EMSTRIDE];
      float n2 = eb[(size_t)c2 * EMSTRIDE];
      float n3 = eb[(size_t)c3 * EMSTRIDE];
      WSTEP(0, e0)
      WSTEP(1, e1)
      WSTEP(2, e2)
      WSTEP(3, e3)
      e0 = n0; e1 = n1; e2 = n2; e3 = n3;
    }
    fin = 0;
epi_w:
    {
      if (tid < 128) ws[(size_t)b * 512 + 384 + tid] = sbuf[fin][lidx(tid)];
    }
  }
}

// ---------------------------------------------------------------------------
// Combine: total = (EwF+EwB)ln2 + log(sum_k WF*WB); best = max_k(VF+VB).
// ---------------------------------------------------------------------------
__global__ __launch_bounds__(128, 1)
void crf_combine_kernel(const float* __restrict__ ws,
                        const int* __restrict__ ewbuf,
                        float* __restrict__ out)
{
  const int b = blockIdx.x, k = threadIdx.x;
  const float* base = ws + (size_t)b * 512;
  float t1 = base[k] * base[128 + k];
  float m1 = base[256 + k] + base[384 + k];
#pragma unroll
  for (int d = 1; d <= 32; d <<= 1) {
    t1 += __shfl_xor(t1, d);
    m1 = fmaxf(m1, __shfl_xor(m1, d));
  }
  __shared__ float rs[2], rm[2];
  const int lane = k & 63, wid = k >> 6;
  if (lane == 0) { rs[wid] = t1; rm[wid] = m1; }
  __syncthreads();
  if (k == 0) {
    const double LN2 = 0.6931471805599453;
    int Et = ewbuf[b] + ewbuf[BATCH + b];
    out[1 + BATCH + b]     = (float)((double)Et * LN2 + (double)__logf(rs[0] + rs[1]));
    out[1 + 2 * BATCH + b] = fmaxf(rm[0], rm[1]);
  }
}

// ---------------------------------------------------------------------------
// loss = mean(total_score - real_path_score)
// ---------------------------------------------------------------------------
__global__ __launch_bounds__(256, 1)
void crf_loss_kernel(float* __restrict__ out)
{
  const int tid = threadIdx.x;
  float dft = out[1 + BATCH + tid] - out[1 + tid];
#pragma unroll
  for (int d = 1; d <= 32; d <<= 1) dft += __shfl_xor(dft, d);
  __shared__ float rs[4];
  const int lane = tid & 63, wid = tid >> 6;
  if (lane == 0) rs[wid] = dft;
  __syncthreads();
  if (tid == 0)
    out[0] = ((rs[0] + rs[1]) + (rs[2] + rs[3])) * (1.0f / BATCH);
}

extern "C" void kernel_launch(void* const* d_in, const int* in_sizes, int n_in,
                              void* d_out, int out_size, void* d_ws, size_t ws_size,
                              hipStream_t stream)
{
  const float* emis   = (const float*)d_in[0];
  const float* mask   = (const float*)d_in[1];
  const int*   tags   = (const int*)d_in[2];
  const float* trans  = (const float*)d_in[3];
  const float* startt = (const float*)d_in[4];
  const float* stopt  = (const float*)d_in[5];
  float* out = (float*)d_out;

  float* wsf   = (float*)d_ws;                 // 256 * 512 floats
  int*   ewbuf = (int*)(wsf + 512 * BATCH);    // 2 * 256 ints

  crf_fat_kernel<<<5 * BATCH, 256, 0, stream>>>(emis, mask, tags, trans,
                                                startt, stopt, wsf, ewbuf, out);
  crf_combine_kernel<<<BATCH, 128, 0, stream>>>(wsf, ewbuf, out);
  crf_loss_kernel<<<1, 256, 0, stream>>>(out);
}